// Round 8
// baseline (77.730 us; speedup 1.0000x reference)
//
#include <hip/hip_runtime.h>
#include <float.h>

#define NB 64
#define NS 512
#define NH 768
#define NL 32
#define NK 8
#define NCH 32          // chunks per sample (16 rows each)

#define OFF_START 0
#define OFF_END   (NB*NS)
#define OFF_SPANS (2*NB*NS)
#define OFF_NSP   (2*NB*NS + NB*NL)
#define OFF_SOH   (2*NB*NS + NB*NL + NB*9)
#define OFF_EOH   (3*NB*NS + NB*NL + NB*9)
#define OFF_LAB   (4*NB*NS + NB*NL + NB*9)

// ---------------- Kernel A: start/end logits + 16-row chunk partial sums -----
// One block = 16 consecutive rows (one chunk). Wave w handles rows base+2w,+2w+1.
__global__ __launch_bounds__(512) void kA(const float* __restrict__ T,
                                          const float* __restrict__ Ws,
                                          const float* __restrict__ We,
                                          const float* __restrict__ bs,
                                          const float* __restrict__ be,
                                          float* __restrict__ out,
                                          float4* __restrict__ wsC,
                                          int* __restrict__ cntA) {
    int j    = blockIdx.x;                 // global chunk id (b*32 + c)
    int wave = threadIdx.x >> 6, lane = threadIdx.x & 63;
    int row  = j * 16 + wave * 2;          // (b*512+s)

    __shared__ float4 smc[8][192];

    const float4* p0  = (const float4*)(T + (size_t)row * NH);
    const float4* p1  = (const float4*)(T + (size_t)(row + 1) * NH);
    const float4* w4s = (const float4*)Ws;
    const float4* w4e = (const float4*)We;
    float as0 = 0.f, ae0 = 0.f, as1 = 0.f, ae1 = 0.f;
    float4 sum[3];
#pragma unroll
    for (int c = 0; c < 3; ++c) {
        float4 t0 = p0[lane + c * 64];
        float4 t1 = p1[lane + c * 64];
        float4 a  = w4s[lane + c * 64];
        float4 bb = w4e[lane + c * 64];
        as0 += t0.x * a.x + t0.y * a.y + t0.z * a.z + t0.w * a.w;
        ae0 += t0.x * bb.x + t0.y * bb.y + t0.z * bb.z + t0.w * bb.w;
        as1 += t1.x * a.x + t1.y * a.y + t1.z * a.z + t1.w * a.w;
        ae1 += t1.x * bb.x + t1.y * bb.y + t1.z * bb.z + t1.w * bb.w;
        sum[c].x = t0.x + t1.x; sum[c].y = t0.y + t1.y;
        sum[c].z = t0.z + t1.z; sum[c].w = t0.w + t1.w;
    }
#pragma unroll
    for (int off = 32; off > 0; off >>= 1) {
        as0 += __shfl_down(as0, off);
        ae0 += __shfl_down(ae0, off);
        as1 += __shfl_down(as1, off);
        ae1 += __shfl_down(ae1, off);
    }
    if (lane == 0) {
        out[OFF_START + row]     = as0 + bs[0];
        out[OFF_START + row + 1] = as1 + bs[0];
        out[OFF_END   + row]     = ae0 + be[0];
        out[OFF_END   + row + 1] = ae1 + be[0];
    }

    smc[wave][lane]       = sum[0];
    smc[wave][lane + 64]  = sum[1];
    smc[wave][lane + 128] = sum[2];
    __syncthreads();
    if (threadIdx.x < 192) {
        float4 v = make_float4(0.f, 0.f, 0.f, 0.f);
#pragma unroll
        for (int w = 0; w < 8; ++w) {
            float4 u = smc[w][threadIdx.x];
            v.x += u.x; v.y += u.y; v.z += u.z; v.w += u.w;
        }
        wsC[(size_t)j * 192 + threadIdx.x] = v;   // 16-row chunk partial (768 floats)
    }
    if (j == 0 && threadIdx.x < NB) cntA[threadIdx.x] = 0;   // reset span counters
}

// Register-resident wave top-8 over 512 values (tie -> lower index, matching
// stable lax.top_k). Lane holds values at indices {lane, lane+64, ..., lane+448}.
__device__ __forceinline__ void waveTop8(const float* __restrict__ g, int lane,
                                         int* __restrict__ dst) {
    float v0 = g[lane],       v1 = g[lane + 64],  v2 = g[lane + 128], v3 = g[lane + 192];
    float v4 = g[lane + 256], v5 = g[lane + 320], v6 = g[lane + 384], v7 = g[lane + 448];
#pragma unroll
    for (int r = 0; r < 8; ++r) {
        float bv = v0; int bi = lane;
        if (v1 > bv) { bv = v1; bi = lane + 64; }
        if (v2 > bv) { bv = v2; bi = lane + 128; }
        if (v3 > bv) { bv = v3; bi = lane + 192; }
        if (v4 > bv) { bv = v4; bi = lane + 256; }
        if (v5 > bv) { bv = v5; bi = lane + 320; }
        if (v6 > bv) { bv = v6; bi = lane + 384; }
        if (v7 > bv) { bv = v7; bi = lane + 448; }
#pragma unroll
        for (int off = 32; off > 0; off >>= 1) {
            float ov = __shfl_xor(bv, off);
            int   oi = __shfl_xor(bi, off);
            if (ov > bv || (ov == bv && oi < bi)) { bv = ov; bi = oi; }
        }
        if (lane == 0) dst[r] = bi;
        if      (bi == lane)       v0 = -FLT_MAX;
        else if (bi == lane + 64)  v1 = -FLT_MAX;
        else if (bi == lane + 128) v2 = -FLT_MAX;
        else if (bi == lane + 192) v3 = -FLT_MAX;
        else if (bi == lane + 256) v4 = -FLT_MAX;
        else if (bi == lane + 320) v5 = -FLT_MAX;
        else if (bi == lane + 384) v6 = -FLT_MAX;
        else if (bi == lane + 448) v7 = -FLT_MAX;
    }
}

#define ACC3(P) do { \
    const float4* _p = (P); \
    float4 _x0 = _p[0], _x1 = _p[64], _x2 = _p[128]; \
    a0.x += _x0.x; a0.y += _x0.y; a0.z += _x0.z; a0.w += _x0.w; \
    a1.x += _x1.x; a1.y += _x1.y; a1.z += _x1.z; a1.w += _x1.w; \
    a2.x += _x2.x; a2.y += _x2.y; a2.z += _x2.z; a2.w += _x2.w; \
} while (0)

// ---------------- Kernel BCD: 9 blocks/sample, redundant heads+topk+merge;
// control block (k==8) writes nsp + single-span/cnt==0 outputs; span blocks
// (k<cnt, multi) compute span logits; the LAST span block to finish (device
// atomic counter) performs the full multi-case assembly. No kD launch.
__global__ __launch_bounds__(512) void kBCD(const float* __restrict__ T,
                                            const float4* __restrict__ wsC,
                                            const float* __restrict__ seq_rep,
                                            const float* __restrict__ W_nspans,
                                            const float* __restrict__ b_nspans,
                                            const float* __restrict__ W_span,
                                            const float* __restrict__ b_span,
                                            float* __restrict__ out,
                                            float* __restrict__ wsLG,
                                            int* __restrict__ cntA) {
    int k = blockIdx.x, b = blockIdx.y;
    int tid = threadIdx.x, wave = tid >> 6, lane = tid & 63;

    __shared__ int    topS[NK], topE[NK];
    __shared__ float  part[6][41];
    __shared__ float  fl[NL], nsp[9];
    __shared__ int    saS[NK], eaS[NK], slS[NK];
    __shared__ int    meta[3];              // ns, cnt, af
    __shared__ float4 sm4[8][192];
    __shared__ float  vec[NH];
    __shared__ float  pl[8][32];
    __shared__ float  lgs[NK][NL];
    __shared__ int    lastFlag;

    // ---- Phase 1 (all blocks, parallel): topk || 41-out GEMV ----
    if (tid < 64) {
        waveTop8(out + OFF_START + b * NS, tid, topS);
    } else if (tid < 128) {
        waveTop8(out + OFF_END + b * NS, tid - 64, topE);
    } else if (tid < 128 + 246) {
        int t = tid - 128, g = t / 41, l = t % 41;
        int h0 = g * 128;
        const float* sr = seq_rep + b * NH;
        float acc = 0.f;
        if (l < 32) {
            for (int h = h0; h < h0 + 128; ++h) acc += sr[h] * W_span[h * NL + l];
        } else {
            int j = l - 32;
            for (int h = h0; h < h0 + 128; ++h) acc += sr[h] * W_nspans[h * 9 + j];
        }
        part[g][l] = acc;
    }
    __syncthreads();
    if (tid < 41) {
        float a = 0.f;
#pragma unroll
        for (int g = 0; g < 6; ++g) a += part[g][tid];
        if (tid < 32) fl[tid] = a + b_span[tid];
        else          nsp[tid - 32] = a + b_nspans[tid - 32];
    }
    __syncthreads();

    // ---- Merge (thread 0, redundant per block) ----
    if (tid == 0) {
        int ns = 0; float bv = nsp[0];
        for (int j = 1; j < 9; ++j) if (nsp[j] > bv) { bv = nsp[j]; ns = j; }

        int ss[NK], es[NK];
        for (int i = 0; i < NK; ++i) {
            ss[i] = (i < ns) ? topS[i] : NS;
            es[i] = (i < ns) ? topE[i] : NS;
        }
        for (int i = 1; i < NK; ++i) {
            int v = ss[i], j = i - 1;
            while (j >= 0 && ss[j] > v) { ss[j + 1] = ss[j]; --j; }
            ss[j + 1] = v;
        }
        for (int i = 1; i < NK; ++i) {
            int v = es[i], j = i - 1;
            while (j >= 0 && es[j] > v) { es[j + 1] = es[j]; --j; }
            es[j + 1] = v;
        }
        int sa[NK], ea[NK];
        for (int i = 0; i < NK; ++i) { sa[i] = 0; ea[i] = 0; }
        int si = 0, ei = 0, nrem = ns, last = 0, cnt = 0;
        while (nrem > 0 && si < ns && ei < ns) {
            int s = ss[si], e = es[ei];
            bool take = (e > s) && (s >= last);
            if (take) { sa[cnt] = s; ea[cnt] = e; last = e; ++cnt; --nrem; }
            if (e > s) ++si;
            if (take || e <= s) ++ei;
        }
        int af = 0; float fv = fl[0];
        for (int l = 1; l < NL; ++l) if (fl[l] > fv) { fv = fl[l]; af = l; }

        meta[0] = ns; meta[1] = cnt; meta[2] = af;
        for (int i = 0; i < NK; ++i) { saS[i] = sa[i]; eaS[i] = ea[i]; }
    }
    __syncthreads();

    int ns = meta[0], cnt = meta[1], af = meta[2];
    bool multi = ns > 1;

    if (k == NK) {   // control block: nsp + single-span / empty-multi outputs
        if (tid < 9) out[OFF_NSP + b * 9 + tid] = nsp[tid];
        if (!multi) {
            if (tid < NL) {
                out[OFF_SPANS + b * NL + tid] = fl[tid];
                out[OFF_LAB   + b * NL + tid] = (tid == af) ? 1.f : 0.f;
            }
            out[OFF_SOH + b * NS + tid] = (tid == topS[0]) ? 1.f : 0.f;
            out[OFF_EOH + b * NS + tid] = (tid == topE[0]) ? 1.f : 0.f;
        } else if (cnt == 0) {
            if (tid < NL) {
                out[OFF_SPANS + b * NL + tid] = 0.f;
                out[OFF_LAB   + b * NL + tid] = 0.f;
            }
            out[OFF_SOH + b * NS + tid] = 0.f;
            out[OFF_EOH + b * NS + tid] = 0.f;
        }
        return;
    }

    if (!multi || k >= cnt) return;   // block-uniform exit

    // ---- Phase 2: span k sum = 16-row chunk partials + edge rows ----
    int s = saS[k], e = eaS[k];
    float4 a0 = make_float4(0.f, 0.f, 0.f, 0.f), a1 = a0, a2 = a0;
    const float4* Tb = (const float4*)(T + (size_t)b * NS * NH);
    const float4* Cb = wsC + (size_t)b * NCH * 192;

    int c0 = (s + 15) >> 4, c1 = e >> 4;
    if (c0 < c1) {
        for (int c = c0 + wave; c < c1; c += 8) ACC3(Cb + (size_t)c * 192 + lane);
        for (int r = s + wave; r < (c0 << 4); r += 8) ACC3(Tb + (size_t)r * 192 + lane);
        for (int r = (c1 << 4) + wave; r < e; r += 8) ACC3(Tb + (size_t)r * 192 + lane);
    } else {
        for (int r = s + wave; r < e; r += 8) ACC3(Tb + (size_t)r * 192 + lane);
    }

    sm4[wave][lane]       = a0;
    sm4[wave][lane + 64]  = a1;
    sm4[wave][lane + 128] = a2;
    __syncthreads();

    if (tid < 192) {
        float inv = 1.f / (float)(e - s);
        float4 v = make_float4(0.f, 0.f, 0.f, 0.f);
#pragma unroll
        for (int w = 0; w < 8; ++w) {
            float4 u = sm4[w][tid];
            v.x += u.x; v.y += u.y; v.z += u.z; v.w += u.w;
        }
        v.x *= inv; v.y *= inv; v.z *= inv; v.w *= inv;
        ((float4*)vec)[tid] = v;
    }
    __syncthreads();

    if (tid < 256) {
        int g = tid >> 5, l = tid & 31;
        float acc = 0.f;
        int h0 = g * 96;
        for (int h = h0; h < h0 + 96; ++h) acc += vec[h] * W_span[h * NL + l];
        pl[g][l] = acc;
    }
    __syncthreads();
    if (tid < 32) {
        float a = b_span[tid];
#pragma unroll
        for (int gg = 0; gg < 8; ++gg) a += pl[gg][tid];
        wsLG[(b * NK + k) * NL + tid] = a;
    }
    // release: wsLG writes (by tid<32) -> fence -> barrier -> counter bump
    __threadfence();
    __syncthreads();
    if (tid == 0) {
        int old = atomicAdd(&cntA[b], 1);
        lastFlag = (old == cnt - 1) ? 1 : 0;
    }
    __syncthreads();
    if (!lastFlag) return;
    __threadfence();   // acquire: other blocks' wsLG rows now visible

    // ---- Assembly (multi, cnt>0), done by the last span block ----
    if (tid < NK) {
        if (tid < cnt) {
            const float* Lp = wsLG + (b * NK + tid) * NL;
            float bv = Lp[0]; int bi = 0;
            for (int l = 0; l < NL; ++l) {
                float x = Lp[l];
                lgs[tid][l] = x;
                if (x > bv) { bv = x; bi = l; }
            }
            slS[tid] = bi;
        } else slS[tid] = -1;
    }
    __syncthreads();
    if (tid < NL) {
        float mx = -FLT_MAX;
        for (int kk = 0; kk < cnt; ++kk) mx = fmaxf(mx, lgs[kk][tid]);
        float lb = 0.f;
        for (int kk = 0; kk < cnt; ++kk) if (slS[kk] == tid) lb = 1.f;
        out[OFF_SPANS + b * NL + tid] = mx;
        out[OFF_LAB   + b * NL + tid] = lb;
    }
    {
        float svv = 0.f, evv = 0.f;
        for (int kk = 0; kk < cnt; ++kk) {
            if (saS[kk] == tid) svv = 1.f;
            if (eaS[kk] == tid) evv = 1.f;
        }
        out[OFF_SOH + b * NS + tid] = svv;
        out[OFF_EOH + b * NS + tid] = evv;
    }
}

extern "C" void kernel_launch(void* const* d_in, const int* in_sizes, int n_in,
                              void* d_out, int out_size, void* d_ws, size_t ws_size,
                              hipStream_t stream) {
    const float* tokens   = (const float*)d_in[0];
    const float* seq_rep  = (const float*)d_in[1];
    const float* W_start  = (const float*)d_in[2];
    const float* b_start  = (const float*)d_in[3];
    const float* W_end    = (const float*)d_in[4];
    const float* b_end    = (const float*)d_in[5];
    const float* W_nspans = (const float*)d_in[6];
    const float* b_nspans = (const float*)d_in[7];
    const float* W_span   = (const float*)d_in[8];
    const float* b_span   = (const float*)d_in[9];
    float* out = (float*)d_out;

    size_t wsCbytes = (size_t)NB * NCH * NH * sizeof(float);     // 6.3 MB chunk partials
    float4* wsC  = (float4*)d_ws;
    float*  wsLG = (float*)((char*)d_ws + wsCbytes);                       // 64*8*32 floats
    int*    cntA = (int*)((char*)d_ws + wsCbytes + NB * NK * NL * sizeof(float)); // 64 ints

    kA<<<(NB * NS) / 16, 512, 0, stream>>>(tokens, W_start, W_end, b_start, b_end,
                                           out, wsC, cntA);
    kBCD<<<dim3(NK + 1, NB), 512, 0, stream>>>(tokens, wsC, seq_rep, W_nspans, b_nspans,
                                               W_span, b_span, out, wsLG, cntA);
}

// Round 9
// 43.869 us; speedup vs baseline: 1.7719x; 1.7719x over previous
//
#include <hip/hip_runtime.h>
#include <float.h>

#define NB 64
#define NS 512
#define NH 768
#define NL 32
#define NK 8
#define NCH 32          // chunks per sample (16 rows each)

#define OFF_START 0
#define OFF_END   (NB*NS)
#define OFF_SPANS (2*NB*NS)
#define OFF_NSP   (2*NB*NS + NB*NL)
#define OFF_SOH   (2*NB*NS + NB*NL + NB*9)
#define OFF_EOH   (3*NB*NS + NB*NL + NB*9)
#define OFF_LAB   (4*NB*NS + NB*NL + NB*9)

// ---------------- Kernel A: start/end logits + 16-row chunk partial sums -----
// One block = 16 consecutive rows (one chunk). Wave w handles rows base+2w,+2w+1.
__global__ __launch_bounds__(512) void kA(const float* __restrict__ T,
                                          const float* __restrict__ Ws,
                                          const float* __restrict__ We,
                                          const float* __restrict__ bs,
                                          const float* __restrict__ be,
                                          float* __restrict__ out,
                                          float4* __restrict__ wsC) {
    int j    = blockIdx.x;                 // global chunk id (b*32 + c)
    int wave = threadIdx.x >> 6, lane = threadIdx.x & 63;
    int row  = j * 16 + wave * 2;          // (b*512+s)

    __shared__ float4 smc[8][192];

    const float4* p0  = (const float4*)(T + (size_t)row * NH);
    const float4* p1  = (const float4*)(T + (size_t)(row + 1) * NH);
    const float4* w4s = (const float4*)Ws;
    const float4* w4e = (const float4*)We;
    float as0 = 0.f, ae0 = 0.f, as1 = 0.f, ae1 = 0.f;
    float4 sum[3];
#pragma unroll
    for (int c = 0; c < 3; ++c) {
        float4 t0 = p0[lane + c * 64];
        float4 t1 = p1[lane + c * 64];
        float4 a  = w4s[lane + c * 64];
        float4 bb = w4e[lane + c * 64];
        as0 += t0.x * a.x + t0.y * a.y + t0.z * a.z + t0.w * a.w;
        ae0 += t0.x * bb.x + t0.y * bb.y + t0.z * bb.z + t0.w * bb.w;
        as1 += t1.x * a.x + t1.y * a.y + t1.z * a.z + t1.w * a.w;
        ae1 += t1.x * bb.x + t1.y * bb.y + t1.z * bb.z + t1.w * bb.w;
        sum[c].x = t0.x + t1.x; sum[c].y = t0.y + t1.y;
        sum[c].z = t0.z + t1.z; sum[c].w = t0.w + t1.w;
    }
#pragma unroll
    for (int off = 32; off > 0; off >>= 1) {
        as0 += __shfl_down(as0, off);
        ae0 += __shfl_down(ae0, off);
        as1 += __shfl_down(as1, off);
        ae1 += __shfl_down(ae1, off);
    }
    if (lane == 0) {
        out[OFF_START + row]     = as0 + bs[0];
        out[OFF_START + row + 1] = as1 + bs[0];
        out[OFF_END   + row]     = ae0 + be[0];
        out[OFF_END   + row + 1] = ae1 + be[0];
    }

    smc[wave][lane]       = sum[0];
    smc[wave][lane + 64]  = sum[1];
    smc[wave][lane + 128] = sum[2];
    __syncthreads();
    if (threadIdx.x < 192) {
        float4 v = make_float4(0.f, 0.f, 0.f, 0.f);
#pragma unroll
        for (int w = 0; w < 8; ++w) {
            float4 u = smc[w][threadIdx.x];
            v.x += u.x; v.y += u.y; v.z += u.z; v.w += u.w;
        }
        wsC[(size_t)j * 192 + threadIdx.x] = v;   // 16-row chunk partial (768 floats)
    }
}

// Register-resident wave top-8 over 512 values (tie -> lower index, matching
// stable lax.top_k). Lane holds values at indices {lane, lane+64, ..., lane+448}.
__device__ __forceinline__ void waveTop8(const float* __restrict__ g, int lane,
                                         int* __restrict__ dst) {
    float v0 = g[lane],       v1 = g[lane + 64],  v2 = g[lane + 128], v3 = g[lane + 192];
    float v4 = g[lane + 256], v5 = g[lane + 320], v6 = g[lane + 384], v7 = g[lane + 448];
#pragma unroll
    for (int r = 0; r < 8; ++r) {
        float bv = v0; int bi = lane;
        if (v1 > bv) { bv = v1; bi = lane + 64; }
        if (v2 > bv) { bv = v2; bi = lane + 128; }
        if (v3 > bv) { bv = v3; bi = lane + 192; }
        if (v4 > bv) { bv = v4; bi = lane + 256; }
        if (v5 > bv) { bv = v5; bi = lane + 320; }
        if (v6 > bv) { bv = v6; bi = lane + 384; }
        if (v7 > bv) { bv = v7; bi = lane + 448; }
#pragma unroll
        for (int off = 32; off > 0; off >>= 1) {
            float ov = __shfl_xor(bv, off);
            int   oi = __shfl_xor(bi, off);
            if (ov > bv || (ov == bv && oi < bi)) { bv = ov; bi = oi; }
        }
        if (lane == 0) dst[r] = bi;
        if      (bi == lane)       v0 = -FLT_MAX;
        else if (bi == lane + 64)  v1 = -FLT_MAX;
        else if (bi == lane + 128) v2 = -FLT_MAX;
        else if (bi == lane + 192) v3 = -FLT_MAX;
        else if (bi == lane + 256) v4 = -FLT_MAX;
        else if (bi == lane + 320) v5 = -FLT_MAX;
        else if (bi == lane + 384) v6 = -FLT_MAX;
        else if (bi == lane + 448) v7 = -FLT_MAX;
    }
}

#define ACC3(P) do { \
    const float4* _p = (P); \
    float4 _x0 = _p[0], _x1 = _p[64], _x2 = _p[128]; \
    a0.x += _x0.x; a0.y += _x0.y; a0.z += _x0.z; a0.w += _x0.w; \
    a1.x += _x1.x; a1.y += _x1.y; a1.z += _x1.z; a1.w += _x1.w; \
    a2.x += _x2.x; a2.y += _x2.y; a2.z += _x2.z; a2.w += _x2.w; \
} while (0)

// ---------------- Kernel BC: 9 blocks per sample, redundant heads+topk+merge;
// block k==8 persists control, blocks k<8 process span k via chunk partials.
// No fences, no atomics — kernel boundary provides cross-block ordering.
__global__ __launch_bounds__(512) void kBC(const float* __restrict__ T,
                                           const float4* __restrict__ wsC,
                                           const float* __restrict__ seq_rep,
                                           const float* __restrict__ W_nspans,
                                           const float* __restrict__ b_nspans,
                                           const float* __restrict__ W_span,
                                           const float* __restrict__ b_span,
                                           float* __restrict__ out,
                                           int* __restrict__ wsI,
                                           float* __restrict__ wsF,
                                           float* __restrict__ wsLG) {
    int k = blockIdx.x, b = blockIdx.y;
    int tid = threadIdx.x, wave = tid >> 6, lane = tid & 63;

    __shared__ int    topS[NK], topE[NK];
    __shared__ float  part[6][41];
    __shared__ float  fl[NL], nsp[9];
    __shared__ int    saS[NK], eaS[NK];
    __shared__ int    meta[3];              // ns, cnt, af
    __shared__ float4 sm4[8][192];
    __shared__ float  vec[NH];
    __shared__ float  pl[8][32];

    // ---- Phase 1 (all blocks, parallel): topk || 41-out GEMV ----
    if (tid < 64) {
        waveTop8(out + OFF_START + b * NS, tid, topS);
    } else if (tid < 128) {
        waveTop8(out + OFF_END + b * NS, tid - 64, topE);
    } else if (tid < 128 + 246) {
        int t = tid - 128, g = t / 41, l = t % 41;
        int h0 = g * 128;
        const float* sr = seq_rep + b * NH;
        float acc = 0.f;
        if (l < 32) {
            for (int h = h0; h < h0 + 128; ++h) acc += sr[h] * W_span[h * NL + l];
        } else {
            int j = l - 32;
            for (int h = h0; h < h0 + 128; ++h) acc += sr[h] * W_nspans[h * 9 + j];
        }
        part[g][l] = acc;
    }
    __syncthreads();
    if (tid < 41) {
        float a = 0.f;
#pragma unroll
        for (int g = 0; g < 6; ++g) a += part[g][tid];
        if (tid < 32) fl[tid] = a + b_span[tid];
        else          nsp[tid - 32] = a + b_nspans[tid - 32];
    }
    __syncthreads();

    // ---- Merge (thread 0, redundant per block) ----
    if (tid == 0) {
        int ns = 0; float bv = nsp[0];
        for (int j = 1; j < 9; ++j) if (nsp[j] > bv) { bv = nsp[j]; ns = j; }

        int ss[NK], es[NK];
        for (int i = 0; i < NK; ++i) {
            ss[i] = (i < ns) ? topS[i] : NS;
            es[i] = (i < ns) ? topE[i] : NS;
        }
        for (int i = 1; i < NK; ++i) {
            int v = ss[i], j = i - 1;
            while (j >= 0 && ss[j] > v) { ss[j + 1] = ss[j]; --j; }
            ss[j + 1] = v;
        }
        for (int i = 1; i < NK; ++i) {
            int v = es[i], j = i - 1;
            while (j >= 0 && es[j] > v) { es[j + 1] = es[j]; --j; }
            es[j + 1] = v;
        }
        int sa[NK], ea[NK];
        for (int i = 0; i < NK; ++i) { sa[i] = 0; ea[i] = 0; }
        int si = 0, ei = 0, nrem = ns, last = 0, cnt = 0;
        while (nrem > 0 && si < ns && ei < ns) {
            int s = ss[si], e = es[ei];
            bool take = (e > s) && (s >= last);
            if (take) { sa[cnt] = s; ea[cnt] = e; last = e; ++cnt; --nrem; }
            if (e > s) ++si;
            if (take || e <= s) ++ei;
        }
        int af = 0; float fv = fl[0];
        for (int l = 1; l < NL; ++l) if (fl[l] > fv) { fv = fl[l]; af = l; }

        meta[0] = ns; meta[1] = cnt; meta[2] = af;
        for (int i = 0; i < NK; ++i) { saS[i] = sa[i]; eaS[i] = ea[i]; }
    }
    __syncthreads();

    int ns = meta[0], cnt = meta[1];

    if (k == NK) {   // control block
        if (tid < 9)  out[OFF_NSP + b * 9 + tid] = nsp[tid];
        if (tid < 32) wsF[b * 32 + tid] = fl[tid];
        if (tid == 0) {
            int* W = wsI + b * 32;
            W[0] = ns; W[1] = cnt; W[2] = meta[2]; W[3] = topS[0]; W[4] = topE[0];
            for (int i = 0; i < NK; ++i) { W[5 + i] = saS[i]; W[13 + i] = eaS[i]; }
        }
        return;
    }

    if (ns <= 1 || k >= cnt) return;   // block-uniform exit

    // ---- Phase 2: span k sum = 16-row chunk partials + edge rows ----
    int s = saS[k], e = eaS[k];
    float4 a0 = make_float4(0.f, 0.f, 0.f, 0.f), a1 = a0, a2 = a0;
    const float4* Tb = (const float4*)(T + (size_t)b * NS * NH);
    const float4* Cb = wsC + (size_t)b * NCH * 192;

    int c0 = (s + 15) >> 4, c1 = e >> 4;
    if (c0 < c1) {
        for (int c = c0 + wave; c < c1; c += 8) ACC3(Cb + (size_t)c * 192 + lane);
        for (int r = s + wave; r < (c0 << 4); r += 8) ACC3(Tb + (size_t)r * 192 + lane);
        for (int r = (c1 << 4) + wave; r < e; r += 8) ACC3(Tb + (size_t)r * 192 + lane);
    } else {
        for (int r = s + wave; r < e; r += 8) ACC3(Tb + (size_t)r * 192 + lane);
    }

    sm4[wave][lane]       = a0;
    sm4[wave][lane + 64]  = a1;
    sm4[wave][lane + 128] = a2;
    __syncthreads();

    if (tid < 192) {
        float inv = 1.f / (float)(e - s);
        float4 v = make_float4(0.f, 0.f, 0.f, 0.f);
#pragma unroll
        for (int w = 0; w < 8; ++w) {
            float4 u = sm4[w][tid];
            v.x += u.x; v.y += u.y; v.z += u.z; v.w += u.w;
        }
        v.x *= inv; v.y *= inv; v.z *= inv; v.w *= inv;
        ((float4*)vec)[tid] = v;
    }
    __syncthreads();

    if (tid < 256) {
        int g = tid >> 5, l = tid & 31;
        float acc = 0.f;
        int h0 = g * 96;
        for (int h = h0; h < h0 + 96; ++h) acc += vec[h] * W_span[h * NL + l];
        pl[g][l] = acc;
    }
    __syncthreads();
    if (tid < 32) {
        float a = b_span[tid];
#pragma unroll
        for (int gg = 0; gg < 8; ++gg) a += pl[gg][tid];
        wsLG[(b * NK + k) * NL + tid] = a;
    }
}

// ---------------- Kernel D: assemble spans/labels/one-hots ----------------
__global__ __launch_bounds__(512) void kD(const int* __restrict__ wsI,
                                          const float* __restrict__ wsF,
                                          const float* __restrict__ wsLG,
                                          float* __restrict__ out) {
    int b = blockIdx.x, t = threadIdx.x;
    const int* W = wsI + b * 32;
    int ns = W[0], cnt = W[1], af = W[2], as_ = W[3], ae_ = W[4];
    bool multi = ns > 1;
    __shared__ int   sa[NK], ea[NK], sl[NK];
    __shared__ float lgs[NK][NL];
    if (t < NK) { sa[t] = W[5 + t]; ea[t] = W[13 + t]; }
    __syncthreads();
    if (t < NK) {
        if (multi && t < cnt) {
            const float* Lp = wsLG + (b * NK + t) * NL;
            float bv = Lp[0]; int bi = 0;
            for (int l = 0; l < NL; ++l) {
                lgs[t][l] = Lp[l];
                if (Lp[l] > bv) { bv = Lp[l]; bi = l; }
            }
            sl[t] = bi;
        } else sl[t] = -1;
    }
    __syncthreads();
    if (t < NL) {
        float sp, lb;
        if (multi) {
            float mx = 0.f;
            if (cnt > 0) {
                mx = -FLT_MAX;
                for (int k = 0; k < cnt; ++k) mx = fmaxf(mx, lgs[k][t]);
            }
            sp = mx;
            lb = 0.f;
            for (int k = 0; k < cnt; ++k) if (sl[k] == t) lb = 1.f;
        } else {
            sp = wsF[b * NL + t];
            lb = (t == af) ? 1.f : 0.f;
        }
        out[OFF_SPANS + b * NL + t] = sp;
        out[OFF_LAB   + b * NL + t] = lb;
    }
    {
        float svv = 0.f, evv = 0.f;
        if (multi) {
            for (int k = 0; k < cnt; ++k) {
                if (sa[k] == t) svv = 1.f;
                if (ea[k] == t) evv = 1.f;
            }
        } else {
            svv = (t == as_) ? 1.f : 0.f;
            evv = (t == ae_) ? 1.f : 0.f;
        }
        out[OFF_SOH + b * NS + t] = svv;
        out[OFF_EOH + b * NS + t] = evv;
    }
}

extern "C" void kernel_launch(void* const* d_in, const int* in_sizes, int n_in,
                              void* d_out, int out_size, void* d_ws, size_t ws_size,
                              hipStream_t stream) {
    const float* tokens   = (const float*)d_in[0];
    const float* seq_rep  = (const float*)d_in[1];
    const float* W_start  = (const float*)d_in[2];
    const float* b_start  = (const float*)d_in[3];
    const float* W_end    = (const float*)d_in[4];
    const float* b_end    = (const float*)d_in[5];
    const float* W_nspans = (const float*)d_in[6];
    const float* b_nspans = (const float*)d_in[7];
    const float* W_span   = (const float*)d_in[8];
    const float* b_span   = (const float*)d_in[9];
    float* out = (float*)d_out;

    size_t wsCbytes = (size_t)NB * NCH * NH * sizeof(float);     // 6.3 MB chunk partials
    float4* wsC  = (float4*)d_ws;
    int*    wsI  = (int*)((char*)d_ws + wsCbytes);                              // 64*32 ints
    float*  wsF  = (float*)((char*)d_ws + wsCbytes + NB * 32 * sizeof(int));    // 64*32 floats
    float*  wsLG = (float*)((char*)d_ws + wsCbytes + NB * 32 * sizeof(int)
                            + NB * NL * sizeof(float));                         // 64*8*32

    kA<<<(NB * NS) / 16, 512, 0, stream>>>(tokens, W_start, W_end, b_start, b_end, out, wsC);
    kBC<<<dim3(NK + 1, NB), 512, 0, stream>>>(tokens, wsC, seq_rep, W_nspans, b_nspans,
                                              W_span, b_span, out, wsI, wsF, wsLG);
    kD<<<NB, 512, 0, stream>>>(wsI, wsF, wsLG, out);
}

// Round 10
// 41.867 us; speedup vs baseline: 1.8566x; 1.0478x over previous
//
#include <hip/hip_runtime.h>
#include <float.h>

#define NB 64
#define NS 512
#define NH 768
#define NL 32
#define NK 8
#define NCH 32          // chunks per sample (16 rows each)

#define OFF_START 0
#define OFF_END   (NB*NS)
#define OFF_SPANS (2*NB*NS)
#define OFF_NSP   (2*NB*NS + NB*NL)
#define OFF_SOH   (2*NB*NS + NB*NL + NB*9)
#define OFF_EOH   (3*NB*NS + NB*NL + NB*9)
#define OFF_LAB   (4*NB*NS + NB*NL + NB*9)

// ---------------- Kernel A: start/end logits + 16-row chunk partial sums -----
// One block = 16 consecutive rows (one chunk). Wave w handles rows base+2w,+2w+1.
// Blocks 0-7 additionally init the spans (-FLT_MAX) / labels (0) output regions
// so kernel 2 can compose them fence-free via atomics / benign stores.
__global__ __launch_bounds__(512) void kA(const float* __restrict__ T,
                                          const float* __restrict__ Ws,
                                          const float* __restrict__ We,
                                          const float* __restrict__ bs,
                                          const float* __restrict__ be,
                                          float* __restrict__ out,
                                          float4* __restrict__ wsC) {
    int j    = blockIdx.x;                 // global chunk id (b*32 + c)
    int wave = threadIdx.x >> 6, lane = threadIdx.x & 63;
    int row  = j * 16 + wave * 2;          // (b*512+s)

    if (j < 4)           out[OFF_SPANS + j * 512 + threadIdx.x] = -FLT_MAX;
    else if (j < 8)      out[OFF_LAB + (j - 4) * 512 + threadIdx.x] = 0.f;

    __shared__ float4 smc[8][192];

    const float4* p0  = (const float4*)(T + (size_t)row * NH);
    const float4* p1  = (const float4*)(T + (size_t)(row + 1) * NH);
    const float4* w4s = (const float4*)Ws;
    const float4* w4e = (const float4*)We;
    float as0 = 0.f, ae0 = 0.f, as1 = 0.f, ae1 = 0.f;
    float4 sum[3];
#pragma unroll
    for (int c = 0; c < 3; ++c) {
        float4 t0 = p0[lane + c * 64];
        float4 t1 = p1[lane + c * 64];
        float4 a  = w4s[lane + c * 64];
        float4 bb = w4e[lane + c * 64];
        as0 += t0.x * a.x + t0.y * a.y + t0.z * a.z + t0.w * a.w;
        ae0 += t0.x * bb.x + t0.y * bb.y + t0.z * bb.z + t0.w * bb.w;
        as1 += t1.x * a.x + t1.y * a.y + t1.z * a.z + t1.w * a.w;
        ae1 += t1.x * bb.x + t1.y * bb.y + t1.z * bb.z + t1.w * bb.w;
        sum[c].x = t0.x + t1.x; sum[c].y = t0.y + t1.y;
        sum[c].z = t0.z + t1.z; sum[c].w = t0.w + t1.w;
    }
#pragma unroll
    for (int off = 32; off > 0; off >>= 1) {
        as0 += __shfl_down(as0, off);
        ae0 += __shfl_down(ae0, off);
        as1 += __shfl_down(as1, off);
        ae1 += __shfl_down(ae1, off);
    }
    if (lane == 0) {
        out[OFF_START + row]     = as0 + bs[0];
        out[OFF_START + row + 1] = as1 + bs[0];
        out[OFF_END   + row]     = ae0 + be[0];
        out[OFF_END   + row + 1] = ae1 + be[0];
    }

    smc[wave][lane]       = sum[0];
    smc[wave][lane + 64]  = sum[1];
    smc[wave][lane + 128] = sum[2];
    __syncthreads();
    if (threadIdx.x < 192) {
        float4 v = make_float4(0.f, 0.f, 0.f, 0.f);
#pragma unroll
        for (int w = 0; w < 8; ++w) {
            float4 u = smc[w][threadIdx.x];
            v.x += u.x; v.y += u.y; v.z += u.z; v.w += u.w;
        }
        wsC[(size_t)j * 192 + threadIdx.x] = v;   // 16-row chunk partial (768 floats)
    }
}

// Register-resident wave top-8 over 512 values (tie -> lower index, matching
// stable lax.top_k). Lane holds values at indices {lane, lane+64, ..., lane+448}.
__device__ __forceinline__ void waveTop8(const float* __restrict__ g, int lane,
                                         int* __restrict__ dst) {
    float v0 = g[lane],       v1 = g[lane + 64],  v2 = g[lane + 128], v3 = g[lane + 192];
    float v4 = g[lane + 256], v5 = g[lane + 320], v6 = g[lane + 384], v7 = g[lane + 448];
#pragma unroll
    for (int r = 0; r < 8; ++r) {
        float bv = v0; int bi = lane;
        if (v1 > bv) { bv = v1; bi = lane + 64; }
        if (v2 > bv) { bv = v2; bi = lane + 128; }
        if (v3 > bv) { bv = v3; bi = lane + 192; }
        if (v4 > bv) { bv = v4; bi = lane + 256; }
        if (v5 > bv) { bv = v5; bi = lane + 320; }
        if (v6 > bv) { bv = v6; bi = lane + 384; }
        if (v7 > bv) { bv = v7; bi = lane + 448; }
#pragma unroll
        for (int off = 32; off > 0; off >>= 1) {
            float ov = __shfl_xor(bv, off);
            int   oi = __shfl_xor(bi, off);
            if (ov > bv || (ov == bv && oi < bi)) { bv = ov; bi = oi; }
        }
        if (lane == 0) dst[r] = bi;
        if      (bi == lane)       v0 = -FLT_MAX;
        else if (bi == lane + 64)  v1 = -FLT_MAX;
        else if (bi == lane + 128) v2 = -FLT_MAX;
        else if (bi == lane + 192) v3 = -FLT_MAX;
        else if (bi == lane + 256) v4 = -FLT_MAX;
        else if (bi == lane + 320) v5 = -FLT_MAX;
        else if (bi == lane + 448) v7 = -FLT_MAX;
        else if (bi == lane + 384) v6 = -FLT_MAX;
    }
}

__device__ __forceinline__ void atomicMaxFloat(float* addr, float val) {
    unsigned int* ua = (unsigned int*)addr;
    unsigned int old = __float_as_uint(*addr);
    while (__uint_as_float(old) < val) {
        unsigned int assumed = old;
        old = atomicCAS(ua, assumed, __float_as_uint(val));
        if (old == assumed) break;
    }
}

#define ACC3(P) do { \
    const float4* _p = (P); \
    float4 _x0 = _p[0], _x1 = _p[64], _x2 = _p[128]; \
    a0.x += _x0.x; a0.y += _x0.y; a0.z += _x0.z; a0.w += _x0.w; \
    a1.x += _x1.x; a1.y += _x1.y; a1.z += _x1.z; a1.w += _x1.w; \
    a2.x += _x2.x; a2.y += _x2.y; a2.z += _x2.z; a2.w += _x2.w; \
} while (0)

// ---------------- Kernel BCD: 9 blocks/sample, redundant heads+topk+merge.
// Control block (k==8): nsp, s_oh/e_oh (multi), and ALL outputs for single /
// cnt==0 cases. Span blocks (k<cnt, multi): span mean via chunk partials ->
// 32 logits -> fence-free composition: atomicMaxFloat into spans (max-reduce,
// payload travels with the atomic) + benign 1.0f store into labels.
__global__ __launch_bounds__(512) void kBCD(const float* __restrict__ T,
                                            const float4* __restrict__ wsC,
                                            const float* __restrict__ seq_rep,
                                            const float* __restrict__ W_nspans,
                                            const float* __restrict__ b_nspans,
                                            const float* __restrict__ W_span,
                                            const float* __restrict__ b_span,
                                            float* __restrict__ out) {
    int k = blockIdx.x, b = blockIdx.y;
    int tid = threadIdx.x, wave = tid >> 6, lane = tid & 63;

    __shared__ int    topS[NK], topE[NK];
    __shared__ float  part[6][41];
    __shared__ float  fl[NL], nsp[9];
    __shared__ int    saS[NK], eaS[NK];
    __shared__ int    meta[3];              // ns, cnt, af
    __shared__ float4 sm4[8][192];
    __shared__ float  vec[NH];
    __shared__ float  pl[8][32];

    // ---- Phase 1 (all blocks, parallel): topk || 41-out GEMV ----
    if (tid < 64) {
        waveTop8(out + OFF_START + b * NS, tid, topS);
    } else if (tid < 128) {
        waveTop8(out + OFF_END + b * NS, tid - 64, topE);
    } else if (tid < 128 + 246) {
        int t = tid - 128, g = t / 41, l = t % 41;
        int h0 = g * 128;
        const float* sr = seq_rep + b * NH;
        float acc = 0.f;
        if (l < 32) {
            for (int h = h0; h < h0 + 128; ++h) acc += sr[h] * W_span[h * NL + l];
        } else {
            int j = l - 32;
            for (int h = h0; h < h0 + 128; ++h) acc += sr[h] * W_nspans[h * 9 + j];
        }
        part[g][l] = acc;
    }
    __syncthreads();
    if (tid < 41) {
        float a = 0.f;
#pragma unroll
        for (int g = 0; g < 6; ++g) a += part[g][tid];
        if (tid < 32) fl[tid] = a + b_span[tid];
        else          nsp[tid - 32] = a + b_nspans[tid - 32];
    }
    __syncthreads();

    // ---- Merge (thread 0, redundant per block) ----
    if (tid == 0) {
        int ns = 0; float bv = nsp[0];
        for (int j = 1; j < 9; ++j) if (nsp[j] > bv) { bv = nsp[j]; ns = j; }

        int ss[NK], es[NK];
        for (int i = 0; i < NK; ++i) {
            ss[i] = (i < ns) ? topS[i] : NS;
            es[i] = (i < ns) ? topE[i] : NS;
        }
        for (int i = 1; i < NK; ++i) {
            int v = ss[i], j = i - 1;
            while (j >= 0 && ss[j] > v) { ss[j + 1] = ss[j]; --j; }
            ss[j + 1] = v;
        }
        for (int i = 1; i < NK; ++i) {
            int v = es[i], j = i - 1;
            while (j >= 0 && es[j] > v) { es[j + 1] = es[j]; --j; }
            es[j + 1] = v;
        }
        int sa[NK], ea[NK];
        for (int i = 0; i < NK; ++i) { sa[i] = 0; ea[i] = 0; }
        int si = 0, ei = 0, nrem = ns, last = 0, cnt = 0;
        while (nrem > 0 && si < ns && ei < ns) {
            int s = ss[si], e = es[ei];
            bool take = (e > s) && (s >= last);
            if (take) { sa[cnt] = s; ea[cnt] = e; last = e; ++cnt; --nrem; }
            if (e > s) ++si;
            if (take || e <= s) ++ei;
        }
        int af = 0; float fv = fl[0];
        for (int l = 1; l < NL; ++l) if (fl[l] > fv) { fv = fl[l]; af = l; }

        meta[0] = ns; meta[1] = cnt; meta[2] = af;
        for (int i = 0; i < NK; ++i) { saS[i] = sa[i]; eaS[i] = ea[i]; }
    }
    __syncthreads();

    int ns = meta[0], cnt = meta[1], af = meta[2];
    bool multi = ns > 1;

    if (k == NK) {   // control block
        if (tid < 9) out[OFF_NSP + b * 9 + tid] = nsp[tid];
        if (!multi) {
            if (tid < NL) {
                out[OFF_SPANS + b * NL + tid] = fl[tid];
                out[OFF_LAB   + b * NL + tid] = (tid == af) ? 1.f : 0.f;
            }
            out[OFF_SOH + b * NS + tid] = (tid == topS[0]) ? 1.f : 0.f;
            out[OFF_EOH + b * NS + tid] = (tid == topE[0]) ? 1.f : 0.f;
        } else {
            // multi: one-hots from merge results (covers cnt==0 -> all zero)
            float svv = 0.f, evv = 0.f;
            for (int kk = 0; kk < cnt; ++kk) {
                if (saS[kk] == tid) svv = 1.f;
                if (eaS[kk] == tid) evv = 1.f;
            }
            out[OFF_SOH + b * NS + tid] = svv;
            out[OFF_EOH + b * NS + tid] = evv;
            if (cnt == 0 && tid < NL) {
                out[OFF_SPANS + b * NL + tid] = 0.f;   // overwrite -FLT_MAX init
                // labels stay 0 from kA init
            }
        }
        return;
    }

    if (!multi || k >= cnt) return;   // block-uniform exit

    // ---- Phase 2: span k sum = 16-row chunk partials + edge rows ----
    int s = saS[k], e = eaS[k];
    float4 a0 = make_float4(0.f, 0.f, 0.f, 0.f), a1 = a0, a2 = a0;
    const float4* Tb = (const float4*)(T + (size_t)b * NS * NH);
    const float4* Cb = wsC + (size_t)b * NCH * 192;

    int c0 = (s + 15) >> 4, c1 = e >> 4;
    if (c0 < c1) {
        for (int c = c0 + wave; c < c1; c += 8) ACC3(Cb + (size_t)c * 192 + lane);
        for (int r = s + wave; r < (c0 << 4); r += 8) ACC3(Tb + (size_t)r * 192 + lane);
        for (int r = (c1 << 4) + wave; r < e; r += 8) ACC3(Tb + (size_t)r * 192 + lane);
    } else {
        for (int r = s + wave; r < e; r += 8) ACC3(Tb + (size_t)r * 192 + lane);
    }

    sm4[wave][lane]       = a0;
    sm4[wave][lane + 64]  = a1;
    sm4[wave][lane + 128] = a2;
    __syncthreads();

    if (tid < 192) {
        float inv = 1.f / (float)(e - s);
        float4 v = make_float4(0.f, 0.f, 0.f, 0.f);
#pragma unroll
        for (int w = 0; w < 8; ++w) {
            float4 u = sm4[w][tid];
            v.x += u.x; v.y += u.y; v.z += u.z; v.w += u.w;
        }
        v.x *= inv; v.y *= inv; v.z *= inv; v.w *= inv;
        ((float4*)vec)[tid] = v;
    }
    __syncthreads();

    if (tid < 256) {
        int g = tid >> 5, l = tid & 31;
        float acc = 0.f;
        int h0 = g * 96;
        for (int h = h0; h < h0 + 96; ++h) acc += vec[h] * W_span[h * NL + l];
        pl[g][l] = acc;
    }
    __syncthreads();
    if (tid < 32) {
        float a = b_span[tid];
#pragma unroll
        for (int gg = 0; gg < 8; ++gg) a += pl[gg][tid];
        // spans: fence-free max-reduce across span blocks
        atomicMaxFloat(&out[OFF_SPANS + b * NL + tid], a);
        // label argmax across lanes 0-31 (tie -> lower index), width-32 butterfly
        float bv = a; int bi = tid;
#pragma unroll
        for (int off = 16; off > 0; off >>= 1) {
            float ov = __shfl_xor(bv, off, 32);
            int   oi = __shfl_xor(bi, off, 32);
            if (ov > bv || (ov == bv && oi < bi)) { bv = ov; bi = oi; }
        }
        if (tid == 0) out[OFF_LAB + b * NL + bi] = 1.f;   // benign racing store of 1.0
    }
}

extern "C" void kernel_launch(void* const* d_in, const int* in_sizes, int n_in,
                              void* d_out, int out_size, void* d_ws, size_t ws_size,
                              hipStream_t stream) {
    const float* tokens   = (const float*)d_in[0];
    const float* seq_rep  = (const float*)d_in[1];
    const float* W_start  = (const float*)d_in[2];
    const float* b_start  = (const float*)d_in[3];
    const float* W_end    = (const float*)d_in[4];
    const float* b_end    = (const float*)d_in[5];
    const float* W_nspans = (const float*)d_in[6];
    const float* b_nspans = (const float*)d_in[7];
    const float* W_span   = (const float*)d_in[8];
    const float* b_span   = (const float*)d_in[9];
    float* out = (float*)d_out;

    float4* wsC = (float4*)d_ws;   // 6.3 MB chunk partials

    kA<<<(NB * NS) / 16, 512, 0, stream>>>(tokens, W_start, W_end, b_start, b_end, out, wsC);
    kBCD<<<dim3(NK + 1, NB), 512, 0, stream>>>(tokens, wsC, seq_rep, W_nspans, b_nspans,
                                               W_span, b_span, out);
}